// Round 8
// baseline (548.181 us; speedup 1.0000x reference)
//
#include <hip/hip_runtime.h>
#include <math.h>

#define N_NODES 50000
#define N_EDGES 800000
#define DIM_IN 64
#define DIM_HID 128
#define DIM_OUT 64

#define NPAD  50176   // 196*256, padded node count for scan
#define NTILES 6250   // 800000/128 edges per tile
#define PBLK   512    // persistent blocks (2/CU at 64KB LDS)

// ws layout (bytes); weights now compact 128-short rows
#define WS_WT    0
#define WS_CNT   81920                    // 320*128*2
#define WS_PREF  (WS_CNT + 200704)
#define WS_BSUM  (WS_PREF + 200704)
#define WS_CUR   (WS_BSUM + 1024)
#define WS_EP    (WS_CUR + 200704)
#define WS_NEED  (WS_EP + 3200000)        // ~3.88 MB

typedef __attribute__((ext_vector_type(8))) short short8;   // 8 bf16 (4 VGPRs)
typedef __attribute__((ext_vector_type(4))) float f32x4;    // MFMA accumulator

union U8 { uint4 u; short8 s; };

__device__ __forceinline__ unsigned short f2bf(float f) {
    unsigned u = __float_as_uint(f);
    return (unsigned short)((u + 0x7fffu + ((u >> 16) & 1u)) >> 16);
}

__device__ __forceinline__ unsigned cvt_pk_bf16(float a, float b) {
#if __has_builtin(__builtin_amdgcn_cvt_pk_bf16_f32)
    auto pk = __builtin_amdgcn_cvt_pk_bf16_f32(a, b);   // lo=a, hi=b
    unsigned d; __builtin_memcpy(&d, &pk, 4);
    return d;
#else
    return (unsigned)f2bf(a) | ((unsigned)f2bf(b) << 16);
#endif
}

__device__ __forceinline__ float exp2_fast(float a) {
#if __has_builtin(__builtin_amdgcn_exp2f)
    return __builtin_amdgcn_exp2f(a);
#else
    return __expf(a * 0.69314718f);
#endif
}

// softplus(x) = max(x,0) + log1p(exp(-|x|)); cubic log1p fit, err ~1.5e-3
__device__ __forceinline__ unsigned sp2(float x0, float x1) {
    const float L2E = 1.44269504f;
    float z0 = exp2_fast(-fabsf(x0) * L2E);
    float z1 = exp2_fast(-fabsf(x1) * L2E);
    float p0 = fmaf(fmaf(fmaf(-0.1011458f, z0, 0.2942925f), z0, -0.5f), z0, 1.0f) * z0;
    float p1 = fmaf(fmaf(fmaf(-0.1011458f, z1, 0.2942925f), z1, -0.5f), z1, 1.0f) * z1;
    return cvt_pk_bf16(fmaxf(x0, 0.0f) + p0, fmaxf(x1, 0.0f) + p1);
}

// Fused: blocks [0,160) convert weights -> bf16 W^T compact [row][128] (layers
// 1,2 K-permuted by pi, proven rounds 4-7); blocks [160,3285) histogram rows.
__global__ void prep_hist(const float* __restrict__ W0,
                          const float* __restrict__ W1,
                          const float* __restrict__ W2,
                          const int* __restrict__ eidx,
                          unsigned short* __restrict__ wt,
                          int* __restrict__ cnt) {
    if (blockIdx.x < 160) {
        int i = blockIdx.x * 256 + threadIdx.x;      // < 40960 = 320*128
        int row = i >> 7, s = i & 127;
        int f = ((s >> 5) << 5) | (((s & 7) >> 2) << 4) | (((s >> 3) & 3) << 2) | (s & 3);
        float v;
        if (row < 128)      v = W0[s * DIM_HID + row];
        else if (row < 256) v = W1[f * DIM_HID + (row - 128)];
        else                v = W2[f * DIM_OUT + (row - 256)];
        wt[i] = f2bf(v);
    } else {
        int e = (blockIdx.x - 160) * 256 + threadIdx.x;
        if (e < N_EDGES) atomicAdd(&cnt[eidx[e]], 1);
    }
}

// block-local exclusive scan + block totals
__global__ void scanA(const int* __restrict__ cnt,
                      int* __restrict__ pref, int* __restrict__ bsum) {
    __shared__ int s[256];
    int t = threadIdx.x, i = blockIdx.x * 256 + t;
    int v = (i < N_NODES) ? cnt[i] : 0;
    s[t] = v;
    __syncthreads();
#pragma unroll
    for (int d = 1; d < 256; d <<= 1) {
        int add = (t >= d) ? s[t - d] : 0;
        __syncthreads();
        s[t] += add;
        __syncthreads();
    }
    pref[i] = s[t] - v;
    if (t == 255) bsum[blockIdx.x] = s[255];
}

// per-block offset = sum(bsum[0..b)) via in-block reduce, then cur = pref + off
__global__ void scanB(const int* __restrict__ pref,
                      const int* __restrict__ bsum,
                      int* __restrict__ cur) {
    __shared__ int s[256];
    int t = threadIdx.x, b = blockIdx.x;
    s[t] = (t < b) ? bsum[t] : 0;
    __syncthreads();
#pragma unroll
    for (int d = 128; d > 0; d >>= 1) {
        if (t < d) s[t] += s[t + d];
        __syncthreads();
    }
    int i = b * 256 + t;
    cur[i] = pref[i] + s[0];
}

// scatter packed (row | col<<16) into sorted-by-row order
__global__ void scatter_pairs(const int* __restrict__ eidx, int* __restrict__ cur,
                              unsigned* __restrict__ ep) {
    int e = blockIdx.x * 256 + threadIdx.x;
    if (e >= N_EDGES) return;
    int row = eidx[e];
    int col = eidx[N_EDGES + e];
    int slot = atomicAdd(&cur[row], 1);
    ep[slot] = (unsigned)row | ((unsigned)col << 16);
}

// ---------- main MLP kernel: persistent blocks, LDS-staged W0/W1 ----------
// Layers 0,1 flipped: mfma(A=weight, B=activation); C col=l16=edge, row=feature;
// inter-layer transform = softplus + cvt_pk + register renaming (pi in weights).
// Layer 2 un-flipped with per-lane sorted-run merge before atomicAdd.
// W0,W1 staged once into LDS with 16B-chunk XOR swizzle (c ^= row&15):
// both staging writes and frag reads hit 8 lanes/bank = structural b128 minimum.
__global__ __launch_bounds__(256, 2)
void edge_mlp_sorted(const float* __restrict__ x,
                     const unsigned* __restrict__ ep,
                     const unsigned short* __restrict__ wt,
                     const float* __restrict__ b0,
                     const float* __restrict__ b1,
                     const float* __restrict__ b2,
                     float* __restrict__ out) {
    __shared__ unsigned short Wlds[256 * 128];   // 64 KiB: W0 rows 0..127, W1 rows 128..255

    const int tid = threadIdx.x;
    for (int g = tid; g < 4096; g += 256) {
        int row = g >> 4, c = g & 15;
        *(uint4*)(Wlds + (row << 7) + ((c ^ (row & 15)) << 3)) =
            *(const uint4*)(wt + (row << 7) + (c << 3));
    }
    __syncthreads();

    const int lane = tid & 63;
    const int w    = tid >> 6;
    const int l16  = lane & 15;
    const int q    = lane >> 4;
    const unsigned short* wt2 = wt + (256 << 7);

    int tile = blockIdx.x;

    // ---- preamble: prefetch tile 0 data ----
    unsigned prv[2]; uint4 pov[2];
    float4 ra[8], rb[8];
    {
        int e0w = tile * 128 + w * 32;
#pragma unroll
        for (int m = 0; m < 2; ++m) {
            prv[m] = ep[e0w + m * 16 + l16];
            pov[m] = *(const uint4*)(ep + e0w + m * 16 + q * 4);
        }
#pragma unroll
        for (int m = 0; m < 2; ++m)
#pragma unroll
            for (int kk = 0; kk < 4; ++kk) {
                int node = (kk >= 2) ? (int)(prv[m] >> 16) : (int)(prv[m] & 0xFFFFu);
                const float* p = x + ((size_t)node << 6) + ((kk & 1) << 5) + (q << 3);
                ra[m * 4 + kk] = *(const float4*)p;
                rb[m * 4 + kk] = *(const float4*)(p + 4);
            }
    }

#pragma unroll 1
    for (; tile < NTILES; tile += PBLK) {
        // consume raw x -> layer-0 B-frags
        short8 hfr[2][4];
#pragma unroll
        for (int m = 0; m < 2; ++m)
#pragma unroll
            for (int kk = 0; kk < 4; ++kk) {
                float4 v0 = ra[m * 4 + kk], v1 = rb[m * 4 + kk];
                U8 t4;
                t4.u.x = cvt_pk_bf16(v0.x, v0.y);
                t4.u.y = cvt_pk_bf16(v0.z, v0.w);
                t4.u.z = cvt_pk_bf16(v1.x, v1.y);
                t4.u.w = cvt_pk_bf16(v1.z, v1.w);
                hfr[m][kk] = t4.s;
            }
        // consume pov -> merge node ids
        int nO[2][4];
#pragma unroll
        for (int m = 0; m < 2; ++m) {
            nO[m][0] = (int)(pov[m].x & 0xFFFFu);
            nO[m][1] = (int)(pov[m].y & 0xFFFFu);
            nO[m][2] = (int)(pov[m].z & 0xFFFFu);
            nO[m][3] = (int)(pov[m].w & 0xFFFFu);
        }

        // issue next-tile ep loads (arrive during layer 0)
        int nt = tile + PBLK;
        int e0n = ((nt < NTILES) ? nt : tile) * 128 + w * 32;
        unsigned prv2[2]; uint4 pov2[2];
#pragma unroll
        for (int m = 0; m < 2; ++m) {
            prv2[m] = ep[e0n + m * 16 + l16];
            pov2[m] = *(const uint4*)(ep + e0n + m * 16 + q * 4);
        }

        // ---- layer 0 (LDS weights, rows 0..127) ----
        unsigned d[2][8][2];
#pragma unroll
        for (int ti = 0; ti < 8; ++ti) {
            f32x4 bb = *(const f32x4*)(b0 + ti * 16 + q * 4);
            f32x4 a0 = bb, a1 = bb;
#pragma unroll
            for (int kk = 0; kk < 4; ++kk) {
                short8 wf = *(const short8*)(Wlds + ((ti * 16 + l16) << 7) +
                                             ((((kk << 2) | q) ^ l16) << 3));
                a0 = __builtin_amdgcn_mfma_f32_16x16x32_bf16(wf, hfr[0][kk], a0, 0, 0, 0);
                a1 = __builtin_amdgcn_mfma_f32_16x16x32_bf16(wf, hfr[1][kk], a1, 0, 0, 0);
            }
            d[0][ti][0] = sp2(a0[0], a0[1]);
            d[0][ti][1] = sp2(a0[2], a0[3]);
            d[1][ti][0] = sp2(a1[0], a1[1]);
            d[1][ti][1] = sp2(a1[2], a1[3]);
        }
#pragma unroll
        for (int m = 0; m < 2; ++m)
#pragma unroll
            for (int kk = 0; kk < 4; ++kk) {
                U8 t4;
                t4.u.x = d[m][2 * kk][0];
                t4.u.y = d[m][2 * kk][1];
                t4.u.z = d[m][2 * kk + 1][0];
                t4.u.w = d[m][2 * kk + 1][1];
                hfr[m][kk] = t4.s;
            }

        // prefetch next-tile x (ep data has arrived; loads cover L1+L2 compute)
#pragma unroll
        for (int m = 0; m < 2; ++m)
#pragma unroll
            for (int kk = 0; kk < 4; ++kk) {
                int node = (kk >= 2) ? (int)(prv2[m] >> 16) : (int)(prv2[m] & 0xFFFFu);
                const float* p = x + ((size_t)node << 6) + ((kk & 1) << 5) + (q << 3);
                ra[m * 4 + kk] = *(const float4*)p;
                rb[m * 4 + kk] = *(const float4*)(p + 4);
            }

        // ---- layer 1 (LDS weights, rows 128..255) ----
#pragma unroll
        for (int ti = 0; ti < 8; ++ti) {
            f32x4 bb = *(const f32x4*)(b1 + ti * 16 + q * 4);
            f32x4 a0 = bb, a1 = bb;
#pragma unroll
            for (int kk = 0; kk < 4; ++kk) {
                short8 wf = *(const short8*)(Wlds + ((128 + ti * 16 + l16) << 7) +
                                             ((((kk << 2) | q) ^ l16) << 3));
                a0 = __builtin_amdgcn_mfma_f32_16x16x32_bf16(wf, hfr[0][kk], a0, 0, 0, 0);
                a1 = __builtin_amdgcn_mfma_f32_16x16x32_bf16(wf, hfr[1][kk], a1, 0, 0, 0);
            }
            d[0][ti][0] = sp2(a0[0], a0[1]);
            d[0][ti][1] = sp2(a0[2], a0[3]);
            d[1][ti][0] = sp2(a1[0], a1[1]);
            d[1][ti][1] = sp2(a1[2], a1[3]);
        }
#pragma unroll
        for (int m = 0; m < 2; ++m)
#pragma unroll
            for (int kk = 0; kk < 4; ++kk) {
                U8 t4;
                t4.u.x = d[m][2 * kk][0];
                t4.u.y = d[m][2 * kk][1];
                t4.u.z = d[m][2 * kk + 1][0];
                t4.u.w = d[m][2 * kk + 1][1];
                hfr[m][kk] = t4.s;
            }

        // ---- layer 2 (global W2, L1-resident) + per-lane run merge + atomics ----
#pragma unroll
        for (int ti = 0; ti < 4; ++ti) {
            float bv = b2[ti * 16 + l16];
            f32x4 a0 = (f32x4){bv, bv, bv, bv};
            f32x4 a1 = a0;
            const unsigned short* Wp = wt2 + ((ti * 16 + l16) << 7) + q * 8;
#pragma unroll
            for (int kk = 0; kk < 4; ++kk) {
                short8 wf = *(const short8*)(Wp + kk * 32);
                a0 = __builtin_amdgcn_mfma_f32_16x16x32_bf16(hfr[0][kk], wf, a0, 0, 0, 0);
                a1 = __builtin_amdgcn_mfma_f32_16x16x32_bf16(hfr[1][kk], wf, a1, 0, 0, 0);
            }
            const int c = ti * 16 + l16;
#pragma unroll
            for (int m = 0; m < 2; ++m) {
                const f32x4& a = m ? a1 : a0;
                int n0 = nO[m][0], n1 = nO[m][1], n2 = nO[m][2], n3 = nO[m][3];
                float s01 = a[0] + a[1], s23 = a[2] + a[3];
                if (n0 == n3 && n0 == n1 && n2 == n3) {
                    atomicAdd(out + (size_t)n0 * DIM_OUT + c, s01 + s23);
                } else {
                    if (n0 == n1) atomicAdd(out + (size_t)n0 * DIM_OUT + c, s01);
                    else {
                        atomicAdd(out + (size_t)n0 * DIM_OUT + c, a[0]);
                        atomicAdd(out + (size_t)n1 * DIM_OUT + c, a[1]);
                    }
                    if (n2 == n3) atomicAdd(out + (size_t)n2 * DIM_OUT + c, s23);
                    else {
                        atomicAdd(out + (size_t)n2 * DIM_OUT + c, a[2]);
                        atomicAdd(out + (size_t)n3 * DIM_OUT + c, a[3]);
                    }
                }
            }
        }

        pov[0] = pov2[0];
        pov[1] = pov2[1];
    }
}

// ---------------- fallback (round-5 proven path, unsorted atomics) ----------------
__global__ __launch_bounds__(256, 4)
void edge_mlp_atomic(const float* __restrict__ x,
                     const int* __restrict__ eidx,
                     const unsigned short* __restrict__ wt,
                     const float* __restrict__ b0,
                     const float* __restrict__ b1,
                     const float* __restrict__ b2,
                     float* __restrict__ out) {
    const int lane = threadIdx.x & 63;
    const int w    = threadIdx.x >> 6;
    const int l16  = lane & 15;
    const int q    = lane >> 4;
    const int e0w  = blockIdx.x * 128 + w * 32;

    const unsigned short* Wt0 = wt;
    const unsigned short* Wt1 = wt + 128 * 128;
    const unsigned short* Wt2 = wt + 256 * 128;

    int nodeR[2], nodeC[2];
#pragma unroll
    for (int m = 0; m < 2; ++m) {
        nodeR[m] = eidx[e0w + m * 16 + l16];
        nodeC[m] = eidx[N_EDGES + e0w + m * 16 + l16];
    }

    short8 hfr[2][4];
#pragma unroll
    for (int m = 0; m < 2; ++m)
#pragma unroll
        for (int kk = 0; kk < 4; ++kk) {
            int node = (kk >= 2) ? nodeC[m] : nodeR[m];
            const float* p = x + (size_t)node * DIM_IN + (kk & 1) * 32 + q * 8;
            float4 v0 = *(const float4*)p;
            float4 v1 = *(const float4*)(p + 4);
            U8 t;
            t.u.x = cvt_pk_bf16(v0.x, v0.y);
            t.u.y = cvt_pk_bf16(v0.z, v0.w);
            t.u.z = cvt_pk_bf16(v1.x, v1.y);
            t.u.w = cvt_pk_bf16(v1.z, v1.w);
            hfr[m][kk] = t.s;
        }

#pragma unroll
    for (int L = 0; L < 2; ++L) {
        const unsigned short* W = L ? Wt1 : Wt0;
        const float* bias = L ? b1 : b0;
        unsigned d[2][8][2];
#pragma unroll
        for (int ti = 0; ti < 8; ++ti) {
            f32x4 bb = *(const f32x4*)(bias + ti * 16 + q * 4);
            f32x4 a0 = bb, a1 = bb;
            const unsigned short* Wp = W + (ti * 16 + l16) * 128 + q * 8;
#pragma unroll
            for (int kk = 0; kk < 4; ++kk) {
                short8 wf = *(const short8*)(Wp + kk * 32);
                a0 = __builtin_amdgcn_mfma_f32_16x16x32_bf16(wf, hfr[0][kk], a0, 0, 0, 0);
                a1 = __builtin_amdgcn_mfma_f32_16x16x32_bf16(wf, hfr[1][kk], a1, 0, 0, 0);
            }
            d[0][ti][0] = sp2(a0[0], a0[1]);
            d[0][ti][1] = sp2(a0[2], a0[3]);
            d[1][ti][0] = sp2(a1[0], a1[1]);
            d[1][ti][1] = sp2(a1[2], a1[3]);
        }
#pragma unroll
        for (int m = 0; m < 2; ++m)
#pragma unroll
            for (int kk = 0; kk < 4; ++kk) {
                U8 t;
                t.u.x = d[m][2 * kk][0];
                t.u.y = d[m][2 * kk][1];
                t.u.z = d[m][2 * kk + 1][0];
                t.u.w = d[m][2 * kk + 1][1];
                hfr[m][kk] = t.s;
            }
    }

    int nodeO[2][4];
#pragma unroll
    for (int m = 0; m < 2; ++m)
#pragma unroll
        for (int r = 0; r < 4; ++r)
            nodeO[m][r] = eidx[e0w + m * 16 + q * 4 + r];

#pragma unroll
    for (int ti = 0; ti < 4; ++ti) {
        float bv = b2[ti * 16 + l16];
        f32x4 a0 = (f32x4){bv, bv, bv, bv};
        f32x4 a1 = a0;
        const unsigned short* Wp = Wt2 + (ti * 16 + l16) * 128 + q * 8;
#pragma unroll
        for (int kk = 0; kk < 4; ++kk) {
            short8 wf = *(const short8*)(Wp + kk * 32);
            a0 = __builtin_amdgcn_mfma_f32_16x16x32_bf16(hfr[0][kk], wf, a0, 0, 0, 0);
            a1 = __builtin_amdgcn_mfma_f32_16x16x32_bf16(hfr[1][kk], wf, a1, 0, 0, 0);
        }
#pragma unroll
        for (int r = 0; r < 4; ++r) {
            atomicAdd(out + (size_t)nodeO[0][r] * DIM_OUT + ti * 16 + l16, a0[r]);
            atomicAdd(out + (size_t)nodeO[1][r] * DIM_OUT + ti * 16 + l16, a1[r]);
        }
    }
}

extern "C" void kernel_launch(void* const* d_in, const int* in_sizes, int n_in,
                              void* d_out, int out_size, void* d_ws, size_t ws_size,
                              hipStream_t stream) {
    const float* x  = (const float*)d_in[0];
    const int*   ei = (const int*)d_in[1];
    const float* W0 = (const float*)d_in[2];
    const float* b0 = (const float*)d_in[3];
    const float* W1 = (const float*)d_in[4];
    const float* b1 = (const float*)d_in[5];
    const float* W2 = (const float*)d_in[6];
    const float* b2 = (const float*)d_in[7];
    float* out = (float*)d_out;

    char* ws = (char*)d_ws;
    unsigned short* wt = (unsigned short*)(ws + WS_WT);
    int* cnt   = (int*)(ws + WS_CNT);
    int* pref  = (int*)(ws + WS_PREF);
    int* bsum  = (int*)(ws + WS_BSUM);
    int* cur   = (int*)(ws + WS_CUR);
    unsigned* ep = (unsigned*)(ws + WS_EP);

    hipMemsetAsync(out, 0, (size_t)N_NODES * DIM_OUT * sizeof(float), stream);

    if (ws_size >= (size_t)WS_NEED) {
        hipMemsetAsync(cnt, 0, NPAD * sizeof(int), stream);
        prep_hist<<<160 + (N_EDGES + 255) / 256, 256, 0, stream>>>(W0, W1, W2, ei, wt, cnt);
        scanA<<<NPAD / 256, 256, 0, stream>>>(cnt, pref, bsum);
        scanB<<<NPAD / 256, 256, 0, stream>>>(pref, bsum, cur);
        scatter_pairs<<<(N_EDGES + 255) / 256, 256, 0, stream>>>(ei, cur, ep);
        edge_mlp_sorted<<<PBLK, 256, 0, stream>>>(x, ep, wt, b0, b1, b2, out);
    } else {
        prep_hist<<<160, 256, 0, stream>>>(W0, W1, W2, ei, wt, cnt);  // prep part only
        edge_mlp_atomic<<<N_EDGES / 128, 256, 0, stream>>>(x, ei, wt, b0, b1, b2, out);
    }
}